// Round 7
// baseline (198.376 us; speedup 1.0000x reference)
//
#include <hip/hip_runtime.h>
#include <hip/hip_bf16.h>

#define SEQ 512
#define NE  192
#define DI  384
#define DS  384
#define DTR 12
#define NC  16      // chunks
#define LC  32      // SEQ / NC
#define DG  4       // channels (d) per scan block
#define SN  6       // states per lane (6*64 = 384 = DS)

#if __has_builtin(__builtin_amdgcn_exp2f)
#define EXP2F(x) __builtin_amdgcn_exp2f(x)
#else
#define EXP2F(x) __expf((x) * 0.69314718056f)
#endif
#define LOG2E 1.44269504089f

__device__ __forceinline__ float fast_sigmoid(float x) {
    return 1.0f / (1.0f + __expf(-x));
}

// DPP add: x + shifted(x); invalid lanes contribute 0 (old = 0, bound_ctrl false).
template<int CTRL>
__device__ __forceinline__ float dpp_add(float x) {
    int v = __builtin_amdgcn_update_dpp(0, __float_as_int(x), CTRL, 0xf, 0xf, false);
    return x + __int_as_float(v);
}
// full 64-lane sum -> lane 63
__device__ __forceinline__ float wave_reduce63(float p) {
    p = dpp_add<0x111>(p);  // row_shr:1
    p = dpp_add<0x112>(p);  // row_shr:2
    p = dpp_add<0x114>(p);  // row_shr:4
    p = dpp_add<0x118>(p);  // row_shr:8
    p = dpp_add<0x142>(p);  // row_bcast:15
    p = dpp_add<0x143>(p);  // row_bcast:31
    return p;
}

// ---------------------------------------------------------------------------
// prep: Wd[n][k] = sum_r W_dt[n][r] * W_xp[r][k]   (384x384, K=12)
// ---------------------------------------------------------------------------
__launch_bounds__(DI)
__global__ void prep_wd(const float* __restrict__ W_dt, const float* __restrict__ W_xp,
                        float* __restrict__ Wd) {
    const int n = blockIdx.x;
    const int k = threadIdx.x;
    float acc = 0.0f;
    #pragma unroll
    for (int r = 0; r < DTR; ++r)
        acc = fmaf(W_dt[n * DTR + r], W_xp[r * DI + k], acc);
    Wd[(size_t)n * DI + k] = acc;
}

// ---------------------------------------------------------------------------
// Tiled fp32 GEMM:  OUT = A (MxK) @ B^T (NxK) [+bias]
// 64x64 tile, BK=64 (float4 staging, 6 iters @ K=384), register prefetch,
// transposed LDS so compute fragments are ds_read_b128.
// MODE 0: n<384 -> fused causal conv4 + SiLU -> u ; n>=384 -> sres=silu(v)
// MODE 1: n<384 -> delta=softplus(v) ; n<768 -> B ; else -> C
//         (B rows <384 from Bsrc0=Wd, rows >=384 from Bsrc1=W_xp, offset DTR)
// MODE 2: plain + bias (out projection)
// ---------------------------------------------------------------------------
template<int MODE>
__launch_bounds__(256)
__global__ void gemm_nt(const float* __restrict__ A,
                        const float* __restrict__ Bsrc0,
                        const float* __restrict__ Bsrc1,
                        const float* __restrict__ bias,
                        const float* __restrict__ conv_w,
                        const float* __restrict__ conv_b,
                        float* __restrict__ O0, float* __restrict__ O1, float* __restrict__ O2,
                        int M, int N, int K) {
    __shared__ float smem[2][64][68];   // [0]=A^T tile, [1]=B^T tile (34.8 KB)
    const int tid = threadIdx.x;
    const int m0 = blockIdx.y * 64;
    const int n0 = blockIdx.x * 64;
    const int tx = tid & 15;        // n micro
    const int ty = tid >> 4;        // m micro (0..15)
    const int sr  = tid >> 4;       // staging row 0..15 (x4 rows)
    const int skq = tid & 15;       // staging k-quad 0..15

    float4 regA[4], regB[4];
    const int NK = K >> 6;

    // block-uniform B source select
    const float* bbase = Bsrc0;
    int boff = 0;
    if (MODE == 1 && n0 >= DI) { bbase = Bsrc1; boff = DTR - DI; }

    auto load_regs = [&](int kk) {
        #pragma unroll
        for (int i = 0; i < 4; ++i) {
            regA[i] = *(const float4*)&A[(size_t)(m0 + sr + 16 * i) * K + kk + 4 * skq];
            regB[i] = *(const float4*)&bbase[(size_t)(n0 + boff + sr + 16 * i) * K + kk + 4 * skq];
        }
    };

    float acc[4][4];
    #pragma unroll
    for (int i = 0; i < 4; ++i)
        #pragma unroll
        for (int j = 0; j < 4; ++j) acc[i][j] = 0.0f;

    load_regs(0);
    for (int it = 0; it < NK; ++it) {
        if (it > 0) __syncthreads();
        #pragma unroll
        for (int i = 0; i < 4; ++i)
            #pragma unroll
            for (int j = 0; j < 4; ++j) {
                smem[0][4 * skq + j][sr + 16 * i] = ((const float*)&regA[i])[j];
                smem[1][4 * skq + j][sr + 16 * i] = ((const float*)&regB[i])[j];
            }
        __syncthreads();
        if (it + 1 < NK) load_regs((it + 1) << 6);
        #pragma unroll
        for (int k = 0; k < 64; ++k) {
            const float4 av = *(const float4*)&smem[0][k][ty * 4];
            const float4 bv = *(const float4*)&smem[1][k][tx * 4];
            acc[0][0] = fmaf(av.x, bv.x, acc[0][0]);
            acc[0][1] = fmaf(av.x, bv.y, acc[0][1]);
            acc[0][2] = fmaf(av.x, bv.z, acc[0][2]);
            acc[0][3] = fmaf(av.x, bv.w, acc[0][3]);
            acc[1][0] = fmaf(av.y, bv.x, acc[1][0]);
            acc[1][1] = fmaf(av.y, bv.y, acc[1][1]);
            acc[1][2] = fmaf(av.y, bv.z, acc[1][2]);
            acc[1][3] = fmaf(av.y, bv.w, acc[1][3]);
            acc[2][0] = fmaf(av.z, bv.x, acc[2][0]);
            acc[2][1] = fmaf(av.z, bv.y, acc[2][1]);
            acc[2][2] = fmaf(av.z, bv.z, acc[2][2]);
            acc[2][3] = fmaf(av.z, bv.w, acc[2][3]);
            acc[3][0] = fmaf(av.w, bv.x, acc[3][0]);
            acc[3][1] = fmaf(av.w, bv.y, acc[3][1]);
            acc[3][2] = fmaf(av.w, bv.z, acc[3][2]);
            acc[3][3] = fmaf(av.w, bv.w, acc[3][3]);
        }
    }

    if (MODE == 0 && n0 < DI) {
        // Fused depthwise causal conv(4) + SiLU -> u, via LDS staging of the
        // xr tile plus 3 halo rows (recomputed; zero for l<0).
        float* S = &smem[0][0][0];   // reuse as [67][68]
        __syncthreads();             // everyone done reading LDS tiles
        #pragma unroll
        for (int i = 0; i < 4; ++i) {
            const int r = ty * 4 + i;
            #pragma unroll
            for (int j = 0; j < 4; ++j) {
                const int c = tx * 4 + j;
                S[(r + 3) * 68 + c] = acc[i][j] + bias[n0 + c];
            }
        }
        if (tid < 192) {
            const int hr = tid >> 6;    // 0..2  -> l = m0-3+hr
            const int hc = tid & 63;
            float v = 0.0f;
            if (m0 > 0) {
                v = bias[n0 + hc];
                const float4* xv = (const float4*)&A[(size_t)(m0 - 3 + hr) * K];
                const float4* wv = (const float4*)&Bsrc0[(size_t)(n0 + hc) * K];
                #pragma unroll 4
                for (int k4 = 0; k4 < K / 4; ++k4) {
                    const float4 xa = xv[k4];
                    const float4 wa = wv[k4];
                    v = fmaf(xa.x, wa.x, v);
                    v = fmaf(xa.y, wa.y, v);
                    v = fmaf(xa.z, wa.z, v);
                    v = fmaf(xa.w, wa.w, v);
                }
            }
            S[hr * 68 + hc] = v;
        }
        __syncthreads();
        #pragma unroll
        for (int j = 0; j < 4; ++j) {
            const int c = tx * 4 + j;
            const int d = n0 + c;
            const float4 w = ((const float4*)conv_w)[d];
            const float cb = conv_b[d];
            #pragma unroll
            for (int i = 0; i < 4; ++i) {
                const int r = ty * 4 + i;
                float xc = cb;
                xc = fmaf(S[(r + 0) * 68 + c], w.x, xc);
                xc = fmaf(S[(r + 1) * 68 + c], w.y, xc);
                xc = fmaf(S[(r + 2) * 68 + c], w.z, xc);
                xc = fmaf(S[(r + 3) * 68 + c], w.w, xc);
                O0[(size_t)(m0 + r) * DI + d] = xc * fast_sigmoid(xc);
            }
        }
        return;
    }

    #pragma unroll
    for (int i = 0; i < 4; ++i) {
        const int gm = m0 + ty * 4 + i;
        #pragma unroll
        for (int j = 0; j < 4; ++j) {
            const int gn = n0 + tx * 4 + j;
            float v = acc[i][j] + (bias ? bias[gn] : 0.0f);
            if (MODE == 0) {
                O1[(size_t)gm * DI + (gn - DI)] = v * fast_sigmoid(v);   // silu(res)
            } else if (MODE == 1) {
                if (gn < DI) {
                    float sp = (v > 20.0f) ? v : log1pf(__expf(v));
                    O0[(size_t)gm * DI + gn] = sp;               // delta
                } else if (gn < 2 * DI) {
                    O1[(size_t)gm * DS + (gn - DI)] = v;         // B
                } else {
                    O2[(size_t)gm * DS + (gn - 2 * DI)] = v;     // C
                }
            } else {
                O0[(size_t)gm * NE + gn] = v;
            }
        }
    }
}

// ---------------------------------------------------------------------------
// Phase A: chunk-local scan. ONE WAVE per block; block = (chunk k, d-group).
// Lane owns 24 states: 4 channels (dd=0..3) x 6 states (n = 6*lane + j).
// ---------------------------------------------------------------------------
__launch_bounds__(64)
__global__ void scanA_kernel(const float* __restrict__ delta,
                             const float* __restrict__ u,
                             const float* __restrict__ Bmat,
                             const float* __restrict__ Cmat,
                             const float* __restrict__ A_log,
                             float* __restrict__ ylocal,
                             float* __restrict__ hend,
                             float* __restrict__ Schunk) {
    const int k    = blockIdx.x;
    const int d0   = blockIdx.y * DG;
    const int lane = threadIdx.x;
    const int l0   = k * LC;
    const int dd   = lane >> 4;      // staging channel 0..3
    const int ls   = lane & 15;      // staging l 0..15 (two rounds)

    __shared__ float4 s_dt4[LC];     // dt per (l, dd)
    __shared__ float4 s_du4[LC];     // dt*u per (l, dd)
    __shared__ float  part[DG][LC];

    float dtk0, dtk1;
    {
        const float dt0 = delta[(size_t)(l0 + ls) * DI + d0 + dd];
        const float uu0 = u[(size_t)(l0 + ls) * DI + d0 + dd];
        const float dt1 = delta[(size_t)(l0 + ls + 16) * DI + d0 + dd];
        const float uu1 = u[(size_t)(l0 + ls + 16) * DI + d0 + dd];
        ((float*)&s_dt4[ls])[dd]      = dt0;
        ((float*)&s_du4[ls])[dd]      = dt0 * uu0;
        ((float*)&s_dt4[ls + 16])[dd] = dt1;
        ((float*)&s_du4[ls + 16])[dd] = dt1 * uu1;
        dtk0 = dt0; dtk1 = dt1;
    }

    float a[DG][SN], h[DG][SN];
    #pragma unroll
    for (int e = 0; e < DG; ++e) {
        const float* ap = A_log + (size_t)(d0 + e) * DS + 6 * lane;
        #pragma unroll
        for (int j = 0; j < SN; ++j) {
            a[e][j] = -__expf(ap[j]) * LOG2E;
            h[e][j] = 0.0f;
        }
    }
    __syncthreads();

    const float* __restrict__ bp = Bmat + (size_t)l0 * DS + 6 * lane;
    const float* __restrict__ cp = Cmat + (size_t)l0 * DS + 6 * lane;

    #pragma unroll 2
    for (int l = 0; l < LC; ++l) {
        const float4 dt4 = s_dt4[l];
        const float4 du4 = s_du4[l];
        const float2 b0 = *(const float2*)(bp + (size_t)l * DS);
        const float2 b1 = *(const float2*)(bp + (size_t)l * DS + 2);
        const float2 b2 = *(const float2*)(bp + (size_t)l * DS + 4);
        const float2 c0 = *(const float2*)(cp + (size_t)l * DS);
        const float2 c1 = *(const float2*)(cp + (size_t)l * DS + 2);
        const float2 c2 = *(const float2*)(cp + (size_t)l * DS + 4);
        const float bb[SN] = {b0.x, b0.y, b1.x, b1.y, b2.x, b2.y};
        const float cc[SN] = {c0.x, c0.y, c1.x, c1.y, c2.x, c2.y};
        #pragma unroll
        for (int e = 0; e < DG; ++e) {
            const float dt = ((const float*)&dt4)[e];
            const float du = ((const float*)&du4)[e];
            float p = 0.0f;
            #pragma unroll
            for (int j = 0; j < SN; ++j) {
                h[e][j] = fmaf(EXP2F(dt * a[e][j]), h[e][j], du * bb[j]);
                p = fmaf(h[e][j], cc[j], p);
            }
            p = wave_reduce63(p);
            if (lane == 63) part[e][l] = p;
        }
    }

    #pragma unroll
    for (int e = 0; e < DG; ++e) {
        float* hp = hend + (size_t)((d0 + e) * NC + k) * DS + 6 * lane;
        *(float2*)(hp + 0) = make_float2(h[e][0], h[e][1]);
        *(float2*)(hp + 2) = make_float2(h[e][2], h[e][3]);
        *(float2*)(hp + 4) = make_float2(h[e][4], h[e][5]);
    }
    {
        float s = dtk0 + dtk1;
        s = dpp_add<0x111>(s);
        s = dpp_add<0x112>(s);
        s = dpp_add<0x114>(s);
        s = dpp_add<0x118>(s);
        if (ls == 15) Schunk[(d0 + dd) * NC + k] = s;
    }
    __syncthreads();
    ylocal[(size_t)(d0 + dd) * SEQ + l0 + ls]      = part[dd][ls];
    ylocal[(size_t)(d0 + dd) * SEQ + l0 + ls + 16] = part[dd][ls + 16];
}

// ---------------------------------------------------------------------------
// Phase B: cross-chunk combine; hend[d,k,:] becomes h_start for chunk k.
// ---------------------------------------------------------------------------
__launch_bounds__(DI)
__global__ void scanB_kernel(const float* __restrict__ A_log,
                             const float* __restrict__ Schunk,
                             float* __restrict__ hend) {
    const int d = blockIdx.x;
    const int n = threadIdx.x;
    const float a = -__expf(A_log[(size_t)d * DS + n]) * LOG2E;
    float H = 0.0f;
    #pragma unroll
    for (int k = 0; k < NC; ++k) {
        const float prev = H;
        const float dtot = EXP2F(a * Schunk[d * NC + k]);
        const float he   = hend[(size_t)(d * NC + k) * DS + n];
        H = fmaf(dtot, H, he);
        hend[(size_t)(d * NC + k) * DS + n] = prev;
    }
}

// ---------------------------------------------------------------------------
// Phase C: correction + gating. Same 4-channel x 6-state single-wave layout.
// ---------------------------------------------------------------------------
__launch_bounds__(64)
__global__ void scanC_kernel(const float* __restrict__ delta,
                             const float* __restrict__ u,
                             const float* __restrict__ Cmat,
                             const float* __restrict__ A_log,
                             const float* __restrict__ Dvec,
                             const float* __restrict__ sres,
                             const float* __restrict__ ylocal,
                             const float* __restrict__ hstart,
                             float* __restrict__ yfin) {
    const int k    = blockIdx.x;
    const int d0   = blockIdx.y * DG;
    const int lane = threadIdx.x;
    const int l0   = k * LC;
    const int dd   = lane >> 4;
    const int ls   = lane & 15;

    __shared__ float4 s_dt4[LC];
    __shared__ float  part[DG][LC];

    if (k > 0) {
        ((float*)&s_dt4[ls])[dd]      = delta[(size_t)(l0 + ls) * DI + d0 + dd];
        ((float*)&s_dt4[ls + 16])[dd] = delta[(size_t)(l0 + ls + 16) * DI + d0 + dd];

        float a[DG][SN], q[DG][SN];
        #pragma unroll
        for (int e = 0; e < DG; ++e) {
            const float* ap = A_log + (size_t)(d0 + e) * DS + 6 * lane;
            const float* hp = hstart + (size_t)((d0 + e) * NC + k) * DS + 6 * lane;
            #pragma unroll
            for (int j = 0; j < SN; ++j) {
                a[e][j] = -__expf(ap[j]) * LOG2E;
                q[e][j] = hp[j];
            }
        }
        __syncthreads();

        const float* __restrict__ cp = Cmat + (size_t)l0 * DS + 6 * lane;

        #pragma unroll 2
        for (int l = 0; l < LC; ++l) {
            const float4 dt4 = s_dt4[l];
            const float2 c0 = *(const float2*)(cp + (size_t)l * DS);
            const float2 c1 = *(const float2*)(cp + (size_t)l * DS + 2);
            const float2 c2 = *(const float2*)(cp + (size_t)l * DS + 4);
            const float cc[SN] = {c0.x, c0.y, c1.x, c1.y, c2.x, c2.y};
            #pragma unroll
            for (int e = 0; e < DG; ++e) {
                const float dt = ((const float*)&dt4)[e];
                float p = 0.0f;
                #pragma unroll
                for (int j = 0; j < SN; ++j) {
                    q[e][j] *= EXP2F(dt * a[e][j]);
                    p = fmaf(q[e][j], cc[j], p);
                }
                p = wave_reduce63(p);
                if (lane == 63) part[e][l] = p;
            }
        }
        __syncthreads();
    }

    const float Dd = Dvec[d0 + dd];
    #pragma unroll
    for (int hh = 0; hh < 2; ++hh) {
        const int l = l0 + ls + hh * 16;
        float y = ylocal[(size_t)(d0 + dd) * SEQ + l];
        if (k > 0) y += part[dd][ls + hh * 16];
        const float uv = u[(size_t)l * DI + d0 + dd];
        const float sr = sres[(size_t)l * DI + d0 + dd];
        yfin[(size_t)l * DI + d0 + dd] = (y + uv * Dd) * sr;
    }
}

// ---------------------------------------------------------------------------
extern "C" void kernel_launch(void* const* d_in, const int* in_sizes, int n_in,
                              void* d_out, int out_size, void* d_ws, size_t ws_size,
                              hipStream_t stream) {
    const float* x      = (const float*)d_in[0];
    const float* W_in   = (const float*)d_in[1];
    const float* b_in   = (const float*)d_in[2];
    const float* conv_w = (const float*)d_in[3];
    const float* conv_b = (const float*)d_in[4];
    const float* W_xp   = (const float*)d_in[5];
    const float* W_dt   = (const float*)d_in[6];
    const float* A_log  = (const float*)d_in[7];
    const float* Dvec   = (const float*)d_in[8];
    const float* W_out  = (const float*)d_in[9];
    const float* b_out  = (const float*)d_in[10];
    float* out = (float*)d_out;

    float* ws = (float*)d_ws;
    const size_t LD = (size_t)SEQ * DI;   // 196608
    float* sres   = ws;
    float* u      = ws + LD;
    float* Bm     = ws + 2 * LD;
    float* Cm     = ws + 3 * LD;
    float* delta  = ws + 4 * LD;
    float* yfin   = ws + 5 * LD;
    float* ylocal = ws + 6 * LD;                    // [DI][SEQ]
    float* hend   = ws + 7 * LD;                    // [DI][NC][DS]
    float* Schunk = hend + (size_t)DI * NC * DS;    // [DI][NC]
    float* Wd     = Schunk + (size_t)DI * NC;       // [DI][DI]

    prep_wd<<<DI, DI, 0, stream>>>(W_dt, W_xp, Wd);
    // in-proj + fused conv/silu (n<384 -> u) and silu(res) (n>=384 -> sres)
    gemm_nt<0><<<dim3(12, 8), 256, 0, stream>>>(x, W_in, nullptr, b_in, conv_w, conv_b,
                                                u, sres, nullptr, SEQ, 2 * DI, NE);
    // x-proj -> delta | B | C
    gemm_nt<1><<<dim3(18, 8), 256, 0, stream>>>(u, Wd, W_xp, nullptr, nullptr, nullptr,
                                                delta, Bm, Cm, SEQ, 3 * DI, DI);
    scanA_kernel<<<dim3(NC, DI / DG), 64, 0, stream>>>(delta, u, Bm, Cm, A_log,
                                                       ylocal, hend, Schunk);
    scanB_kernel<<<DI, DI, 0, stream>>>(A_log, Schunk, hend);
    scanC_kernel<<<dim3(NC, DI / DG), 64, 0, stream>>>(delta, u, Cm, A_log, Dvec, sres,
                                                       ylocal, hend, yfin);
    gemm_nt<2><<<dim3(3, 8), 256, 0, stream>>>(yfin, W_out, nullptr, b_out, nullptr, nullptr,
                                               out, nullptr, nullptr, SEQ, NE, DI);
}